// Round 2
// baseline (78.698 us; speedup 1.0000x reference)
//
#include <hip/hip_runtime.h>

#define H 1024
#define W 1024
#define NB 8
#define PADR 4
#define TY 8
#define NT 256

__global__ void ncc_zero(double* acc) { *acc = 0.0; }

__global__ void ncc_finalize(const double* __restrict__ acc, float* __restrict__ out) {
    out[0] = 1.0f - (float)(*acc * (1.0 / 8388608.0));  // 8*1024*1024 pixels
}

// Horizontal 9-tap sums over own 4 cols using wave shuffles for the +-4 col halo.
// S[0..3] = vertical sums for cols x0..x0+3; Q[0..3] = edge-lane halo vertical sums
// (left halo cols for lane 0, right halo cols for lane 63).
#define HPASS(S, Q, O) do {                                                              \
    float l0 = __shfl_up(S[0], 1), l1 = __shfl_up(S[1], 1);                              \
    float l2 = __shfl_up(S[2], 1), l3 = __shfl_up(S[3], 1);                              \
    float r0 = __shfl_down(S[0], 1), r1 = __shfl_down(S[1], 1);                          \
    float r2 = __shfl_down(S[2], 1), r3 = __shfl_down(S[3], 1);                          \
    l0 = ledge ? Q[0] : l0; l1 = ledge ? Q[1] : l1;                                      \
    l2 = ledge ? Q[2] : l2; l3 = ledge ? Q[3] : l3;                                      \
    r0 = redge ? Q[0] : r0; r1 = redge ? Q[1] : r1;                                      \
    r2 = redge ? Q[2] : r2; r3 = redge ? Q[3] : r3;                                      \
    float s = l0 + l1 + l2 + l3 + S[0] + S[1] + S[2] + S[3] + r0;                        \
    O[0] = s; s += r1 - l0; O[1] = s; s += r2 - l1; O[2] = s; s += r3 - l2; O[3] = s;    \
} while (0)

__global__ __launch_bounds__(NT) void ncc_main(
    const float* __restrict__ Jg,  // y_pred
    const float* __restrict__ Ig,  // y_true
    double* __restrict__ acc)
{
    const int b    = blockIdx.x;
    const int y0   = blockIdx.y * TY;
    const int t    = threadIdx.x;
    const int lane = t & 63;
    const int x0   = t << 2;                       // 4 cols per thread, full width per block
    const bool ledge = (lane == 0), redge = (lane == 63);
    const int  hx   = x0 + (ledge ? -4 : 4);       // halo float4 col base for edge lanes
    const bool hval = (ledge || redge) && ((unsigned)hx < (unsigned)W);

    const float* Ib = Ig + (size_t)b * (H * W);
    const float* Jb = Jg + (size_t)b * (H * W);

    // own vertical window sums (5 quantities x 4 cols)
    float sI[4]={0,0,0,0}, sJ[4]={0,0,0,0}, sII[4]={0,0,0,0}, sJJ[4]={0,0,0,0}, sIJ[4]={0,0,0,0};
    // halo vertical window sums (edge lanes only; stay 0 elsewhere)
    float qI[4]={0,0,0,0}, qJ[4]={0,0,0,0}, qII[4]={0,0,0,0}, qJJ[4]={0,0,0,0}, qIJ[4]={0,0,0,0};

    // initial vertical window: input rows [y0-4, y0+4], zero-padded
    for (int r = y0 - PADR; r <= y0 + PADR; ++r) {
        float4 iv = {0,0,0,0}, jv = {0,0,0,0}, ih = {0,0,0,0}, jh = {0,0,0,0};
        const bool rv = ((unsigned)r < (unsigned)H);
        if (rv) {
            iv = *(const float4*)(Ib + r * W + x0);
            jv = *(const float4*)(Jb + r * W + x0);
        }
        if (rv && hval) {
            ih = *(const float4*)(Ib + r * W + hx);
            jh = *(const float4*)(Jb + r * W + hx);
        }
        const float fi[4]={iv.x,iv.y,iv.z,iv.w}, fj[4]={jv.x,jv.y,jv.z,jv.w};
        const float gi[4]={ih.x,ih.y,ih.z,ih.w}, gj[4]={jh.x,jh.y,jh.z,jh.w};
        #pragma unroll
        for (int c = 0; c < 4; ++c) {
            sI[c]+=fi[c]; sJ[c]+=fj[c]; sII[c]+=fi[c]*fi[c]; sJJ[c]+=fj[c]*fj[c]; sIJ[c]+=fi[c]*fj[c];
            qI[c]+=gi[c]; qJ[c]+=gj[c]; qII[c]+=gi[c]*gi[c]; qJJ[c]+=gj[c]*gj[c]; qIJ[c]+=gi[c]*gj[c];
        }
    }

    const float inv = 1.0f / 81.0f;
    float accv = 0.0f;

    for (int y = y0; y < y0 + TY; ++y) {
        // ---- prefetch the slide rows (add y+5, sub y-4) at loop top; consumed after compute
        const int ra = y + PADR + 1;
        const int rs = y - PADR;
        float4 iva={0,0,0,0}, jva={0,0,0,0}, ivs={0,0,0,0}, jvs={0,0,0,0};
        float4 iha={0,0,0,0}, jha={0,0,0,0}, ihs={0,0,0,0}, jhs={0,0,0,0};
        if (ra < H) {
            iva = *(const float4*)(Ib + ra * W + x0);
            jva = *(const float4*)(Jb + ra * W + x0);
        }
        if (rs >= 0) {
            ivs = *(const float4*)(Ib + rs * W + x0);
            jvs = *(const float4*)(Jb + rs * W + x0);
        }
        if (hval) {
            if (ra < H) {
                iha = *(const float4*)(Ib + ra * W + hx);
                jha = *(const float4*)(Jb + ra * W + hx);
            }
            if (rs >= 0) {
                ihs = *(const float4*)(Ib + rs * W + hx);
                jhs = *(const float4*)(Jb + rs * W + hx);
            }
        }

        // ---- horizontal 9-tap via shuffles, then per-pixel cc
        float hI_[4], hJ_[4], hII_[4], hJJ_[4], hIJ_[4];
        HPASS(sI,  qI,  hI_);
        HPASS(sJ,  qJ,  hJ_);
        HPASS(sII, qII, hII_);
        HPASS(sJJ, qJJ, hJJ_);
        HPASS(sIJ, qIJ, hIJ_);

        #pragma unroll
        for (int c = 0; c < 4; ++c) {
            const float uI    = hI_[c] * inv;
            const float uJ    = hJ_[c] * inv;
            const float cross = hIJ_[c] * inv - uI * uJ;
            const float Iv    = hII_[c] * inv - uI * uI;
            const float Jv    = hJJ_[c] * inv - uJ * uJ;
            accv += cross * rsqrtf(fmaxf(Iv * Jv, 1e-7f));
        }

        // ---- apply the slide (zeros where out of range -> unconditional)
        {
            const float fa[4]={iva.x,iva.y,iva.z,iva.w}, ja[4]={jva.x,jva.y,jva.z,jva.w};
            const float fs[4]={ivs.x,ivs.y,ivs.z,ivs.w}, js[4]={jvs.x,jvs.y,jvs.z,jvs.w};
            const float ga[4]={iha.x,iha.y,iha.z,iha.w}, ka[4]={jha.x,jha.y,jha.z,jha.w};
            const float gs[4]={ihs.x,ihs.y,ihs.z,ihs.w}, ks[4]={jhs.x,jhs.y,jhs.z,jhs.w};
            #pragma unroll
            for (int c = 0; c < 4; ++c) {
                sI[c]  += fa[c] - fs[c];
                sJ[c]  += ja[c] - js[c];
                sII[c] += fa[c]*fa[c] - fs[c]*fs[c];
                sJJ[c] += ja[c]*ja[c] - js[c]*js[c];
                sIJ[c] += fa[c]*ja[c] - fs[c]*js[c];
                qI[c]  += ga[c] - gs[c];
                qJ[c]  += ka[c] - ks[c];
                qII[c] += ga[c]*ga[c] - gs[c]*gs[c];
                qJJ[c] += ka[c]*ka[c] - ks[c]*ks[c];
                qIJ[c] += ga[c]*ka[c] - gs[c]*ks[c];
            }
        }
    }

    // wave reduce (64 lanes), one double atomic per wave
    #pragma unroll
    for (int off = 32; off > 0; off >>= 1)
        accv += __shfl_down(accv, off);
    if (lane == 0)
        atomicAdd(acc, (double)accv);
}

extern "C" void kernel_launch(void* const* d_in, const int* in_sizes, int n_in,
                              void* d_out, int out_size, void* d_ws, size_t ws_size,
                              hipStream_t stream) {
    const float* y_pred = (const float*)d_in[0];  // Ji
    const float* y_true = (const float*)d_in[1];  // Ii
    float* out = (float*)d_out;
    double* accp = (double*)d_ws;

    ncc_zero<<<dim3(1), dim3(1), 0, stream>>>(accp);
    dim3 grid(NB, H / TY);  // 8 x 128 = 1024 blocks, 4 waves each, no barriers
    ncc_main<<<grid, dim3(NT), 0, stream>>>(y_pred, y_true, accp);
    ncc_finalize<<<dim3(1), dim3(1), 0, stream>>>(accp, out);
}